// Round 4
// baseline (928.736 us; speedup 1.0000x reference)
//
#include <hip/hip_runtime.h>
#include <stdint.h>

#define MDIM 8192
#define KDIM 4096
#define NDIM 4096
#define MAXFLAGS (2 * 1024 * 1024)

typedef int i32x4 __attribute__((ext_vector_type(4)));

#define VMCNT(n) asm volatile("s_waitcnt vmcnt(" #n ")" ::: "memory")
#define LGKMCNT0 asm volatile("s_waitcnt lgkmcnt(0)" ::: "memory")
#define SB0 __builtin_amdgcn_sched_barrier(0)

__device__ __forceinline__ void gl2lds16(const void* g, void* l) {
  __builtin_amdgcn_global_load_lds(
      (const __attribute__((address_space(1))) void*)(uintptr_t)(g),
      (__attribute__((address_space(3))) void*)(uintptr_t)(l), 16, 0, 0);
}

// ---------------- ternarize + transpose: Qt[n][k] = clip(rint(W[k][n]),-1,1) ----------------
__global__ __launch_bounds__(256) void k_tern(const float* __restrict__ W,
                                              int8_t* __restrict__ Qt) {
  __shared__ int8_t t[64][65];
  const int n0 = blockIdx.x * 64;
  const int k0 = blockIdx.y * 64;
  const int tid = threadIdx.x;
  const int c = tid & 63;
  const int r0 = tid >> 6;
#pragma unroll
  for (int i = 0; i < 16; ++i) {
    int r = (i << 2) + r0;
    float w = W[(size_t)(k0 + r) * NDIM + (n0 + c)];
    float q = fminf(1.f, fmaxf(-1.f, rintf(w)));  // rint = round-half-even, matches jnp.round
    t[r][c] = (int8_t)(int)q;
  }
  __syncthreads();
#pragma unroll
  for (int i = 0; i < 16; ++i) {
    int r = (i << 2) + r0;
    Qt[(size_t)(n0 + r) * KDIM + (k0 + c)] = t[c][r];
  }
}

// ---------------- quantize x to 3 signed base-256 digit planes of round(x * 2^19) ----------------
__global__ __launch_bounds__(256) void k_quant(const float* __restrict__ x,
                                               int8_t* __restrict__ dig) {
  const size_t P = (size_t)MDIM * KDIM;
  size_t i = ((size_t)blockIdx.x * 256 + threadIdx.x) * 4;
  float4 v = *(const float4*)(x + i);
  float f[4] = {v.x, v.y, v.z, v.w};
  int8_t dd[3][4];
#pragma unroll
  for (int j = 0; j < 4; ++j) {
    long long s = __double2ll_rn((double)f[j] * 524288.0);  // exact: f32->f64, *2^19
    int8_t d0 = (int8_t)s; s = (s - d0) >> 8;
    int8_t d1 = (int8_t)s; s = (s - d1) >> 8;
    int8_t d2 = (int8_t)s;  // |x|<8 guaranteed-fit
    dd[0][j] = d0; dd[1][j] = d1; dd[2][j] = d2;
  }
#pragma unroll
  for (int p = 0; p < 3; ++p) {
    char4 c4; c4.x = dd[p][0]; c4.y = dd[p][1]; c4.z = dd[p][2]; c4.w = dd[p][3];
    *(char4*)(dig + p * P + i) = c4;
  }
}

__global__ void k_zero(int* c) {
  if (threadIdx.x == 0 && blockIdx.x == 0) *c = 0;
}

// ---------------- layer 1: 3 digit planes x Qt -> sign -> h0 (i8), flag |sum|<=2048 ----------------
// 4-buffer ring, BK=64, counted per-role vmcnt. tile 64x128, 8 waves, per-wave 32x32.
__global__ __launch_bounds__(512, 4) void k_gemm_l1(const int8_t* __restrict__ dig,
                                                    const int8_t* __restrict__ Qt,
                                                    int8_t* __restrict__ h,
                                                    int* __restrict__ cnt,
                                                    int2* __restrict__ flags) {
  __shared__ __align__(16) int8_t As[4][3][64][64];   // 48KB
  __shared__ __align__(16) int8_t Bs[4][128][64];     // 32KB
  const int tid = threadIdx.x;
  const int w = tid >> 6, l = tid & 63;
  const size_t P = (size_t)MDIM * KDIM;

  const int nwg = gridDim.x;                                   // 4096, %8==0
  const int wg = (blockIdx.x & 7) * (nwg >> 3) + (blockIdx.x >> 3);
  const int NB = NDIM / 128;                                   // 32
  const int mb = wg / NB, nb = wg % NB;

  // staging addressing: lane l covers (row_in = l>>2, swizzled 16B col)
  const int srow_in = l >> 2;                        // 0..15
  const int scol = (((l & 3) ^ ((l >> 3) & 3)) << 4);  // pre-swizzled k-byte
  const bool wA = (w < 6);
  // A-waves (0..5): loads i0=w*2, i1=w*2+1 -> plane p=i>>2, row chunk i&3
  // B-waves (6,7): loads j=(w-6)*4+q, q=0..3
  const int8_t* ga0 = nullptr; const int8_t* ga1 = nullptr;
  const int8_t* gb0 = nullptr; const int8_t* gb1 = nullptr;
  const int8_t* gb2 = nullptr; const int8_t* gb3 = nullptr;
  if (wA) {
    int i0 = w * 2, i1 = w * 2 + 1;
    ga0 = dig + (size_t)(i0 >> 2) * P + (size_t)(mb * 64 + (i0 & 3) * 16 + srow_in) * KDIM + scol;
    ga1 = dig + (size_t)(i1 >> 2) * P + (size_t)(mb * 64 + (i1 & 3) * 16 + srow_in) * KDIM + scol;
  } else {
    int j = (w - 6) * 4;
    gb0 = Qt + (size_t)(nb * 128 + (j + 0) * 16 + srow_in) * KDIM + scol;
    gb1 = Qt + (size_t)(nb * 128 + (j + 1) * 16 + srow_in) * KDIM + scol;
    gb2 = Qt + (size_t)(nb * 128 + (j + 2) * 16 + srow_in) * KDIM + scol;
    gb3 = Qt + (size_t)(nb * 128 + (j + 3) * 16 + srow_in) * KDIM + scol;
  }

  i32x4 acc[3][2][2];
#pragma unroll
  for (int p = 0; p < 3; ++p)
#pragma unroll
    for (int mi = 0; mi < 2; ++mi)
#pragma unroll
      for (int ni = 0; ni < 2; ++ni) acc[p][mi][ni] = (i32x4){0, 0, 0, 0};

  const int wr = (w >> 2) * 32;
  const int wc = (w & 3) * 32;
  const int kg = l >> 4;
  const int fsw = ((kg ^ ((l >> 1) & 3)) << 4);  // swizzled frag 16B slot (low4 of row = l&15)

  auto stage = [&](int buf, int kk) {
    if (wA) {
      int8_t* d0 = &As[buf][0][0][0] + (w * 2) * 1024;
      gl2lds16(ga0 + kk, d0);
      gl2lds16(ga1 + kk, d0 + 1024);
    } else {
      int8_t* d0 = &Bs[buf][0][0] + ((w - 6) * 4) * 1024;
      gl2lds16(gb0 + kk, d0);
      gl2lds16(gb1 + kk, d0 + 1024);
      gl2lds16(gb2 + kk, d0 + 2048);
      gl2lds16(gb3 + kk, d0 + 3072);
    }
  };

  auto compute = [&](int buf) {
    i32x4 b[2];
#pragma unroll
    for (int ni = 0; ni < 2; ++ni) {
      int nr = wc + ni * 16 + (l & 15);
      b[ni] = *(const i32x4*)&Bs[buf][nr][fsw];
    }
    __builtin_amdgcn_s_setprio(1);
#pragma unroll
    for (int p = 0; p < 3; ++p)
#pragma unroll
      for (int mi = 0; mi < 2; ++mi) {
        int ar = wr + mi * 16 + (l & 15);
        i32x4 a = *(const i32x4*)&As[buf][p][ar][fsw];
#pragma unroll
        for (int ni = 0; ni < 2; ++ni)
          acc[p][mi][ni] =
              __builtin_amdgcn_mfma_i32_16x16x64_i8(a, b[ni], acc[p][mi][ni], 0, 0, 0);
      }
    __builtin_amdgcn_s_setprio(0);
  };

  const int NT = KDIM / 64;  // 64
  stage(0, 0); stage(1, 64); stage(2, 128); stage(3, 192);
  if (wA) VMCNT(6); else VMCNT(12);   // tile 0 landed (3 tiles in flight)
  SB0;
  __builtin_amdgcn_s_barrier();

  for (int t = 0; t < NT; ++t) {
    compute(t & 3);
    if (t == NT - 1) break;
    LGKMCNT0; SB0;
    __builtin_amdgcn_s_barrier();               // all waves done reading buf t&3
    if (t + 4 < NT) {
      stage(t & 3, (t + 4) * 64);               // refill with tile t+4
      if (wA) VMCNT(6); else VMCNT(12);         // tile t+1 landed
    } else if (t + 3 < NT) {
      if (wA) VMCNT(4); else VMCNT(8);
    } else if (t + 2 < NT) {
      if (wA) VMCNT(2); else VMCNT(4);
    } else {
      VMCNT(0);
    }
    SB0;
    __builtin_amdgcn_s_barrier();               // tile t+1 visible to all
  }

  const int mbase = mb * 64 + wr + ((l >> 4) << 2);
  const int nbase = nb * 128 + wc + (l & 15);
#pragma unroll
  for (int mi = 0; mi < 2; ++mi)
#pragma unroll
    for (int ni = 0; ni < 2; ++ni)
#pragma unroll
      for (int j = 0; j < 4; ++j) {
        int s0 = acc[0][mi][ni][j], s1 = acc[1][mi][ni][j];
        int s2 = acc[2][mi][ni][j];
        double d = ((double)s2 * 256.0 + (double)s1) * 256.0 + (double)s0;
        int sg = (d > 0.0) - (d < 0.0);
        int row = mbase + mi * 16 + j;
        int col = nbase + ni * 16;
        h[(size_t)row * NDIM + col] = (int8_t)sg;
        if (fabs(d) <= 2048.0) {  // certified: |d - 2^19*exact| <= 0.5*4096
          int idx = atomicAdd(cnt, 1);
          if (idx < MAXFLAGS) flags[idx] = make_int2(row, col);
        }
      }
}

// ---------------- exact f64 fixup of flagged (row,col) outputs ----------------
__global__ __launch_bounds__(256) void k_fixup(const float* __restrict__ x,
                                               const int8_t* __restrict__ Qt,
                                               const int* __restrict__ cnt,
                                               const int2* __restrict__ flags,
                                               int8_t* __restrict__ h) {
  __shared__ double red[256];
  int n = *cnt;
  if (n > MAXFLAGS) n = MAXFLAGS;
  for (int i = blockIdx.x; i < n; i += gridDim.x) {
    int2 rc = flags[i];
    const float* xr = x + (size_t)rc.x * KDIM;
    const int8_t* qr = Qt + (size_t)rc.y * KDIM;
    double s = 0.0;
    for (int k = threadIdx.x; k < KDIM; k += 256)
      s += (double)xr[k] * (double)qr[k];
    red[threadIdx.x] = s;
    __syncthreads();
#pragma unroll
    for (int st = 128; st > 0; st >>= 1) {
      if (threadIdx.x < st) red[threadIdx.x] += red[threadIdx.x + st];
      __syncthreads();
    }
    if (threadIdx.x == 0) {
      double d = red[0];
      h[(size_t)rc.x * NDIM + rc.y] = (int8_t)((d > 0.0) - (d < 0.0));
    }
    __syncthreads();
  }
}

// ---------------- layers 2/3: h (i8 +-1/0) x Qt -> sign -> i8 or f32 ----------------
// 4-buffer ring, BK=64, counted vmcnt. tile 128x128, 8 waves, per-wave 64x32.
template <int F32OUT>
__global__ __launch_bounds__(512, 4) void k_gemm_bin(const int8_t* __restrict__ A,
                                                     const int8_t* __restrict__ Qt,
                                                     void* __restrict__ outp) {
  __shared__ __align__(16) int8_t As[4][128][64];   // 32KB
  __shared__ __align__(16) int8_t Bs[4][128][64];   // 32KB
  const int tid = threadIdx.x;
  const int w = tid >> 6, l = tid & 63;

  const int nwg = gridDim.x;                                   // 2048, %8==0
  const int wg = (blockIdx.x & 7) * (nwg >> 3) + (blockIdx.x >> 3);
  const int NB = NDIM / 128;                                   // 32
  const int mb = wg / NB, nb = wg % NB;

  const int srow_in = l >> 2;
  const int scol = (((l & 3) ^ ((l >> 3) & 3)) << 4);
  const int8_t* ga = A + (size_t)(mb * 128 + w * 16 + srow_in) * KDIM + scol;
  const int8_t* gb = Qt + (size_t)(nb * 128 + w * 16 + srow_in) * KDIM + scol;

  i32x4 acc[4][2];
#pragma unroll
  for (int mi = 0; mi < 4; ++mi)
#pragma unroll
    for (int ni = 0; ni < 2; ++ni) acc[mi][ni] = (i32x4){0, 0, 0, 0};

  const int wr = (w >> 2) * 64, wc = (w & 3) * 32;
  const int kg = l >> 4;
  const int fsw = ((kg ^ ((l >> 1) & 3)) << 4);

  auto stage = [&](int buf, int kk) {
    gl2lds16(ga + kk, &As[buf][0][0] + w * 1024);
    gl2lds16(gb + kk, &Bs[buf][0][0] + w * 1024);
  };

  auto compute = [&](int buf) {
    i32x4 b[2];
#pragma unroll
    for (int ni = 0; ni < 2; ++ni) {
      int nr = wc + ni * 16 + (l & 15);
      b[ni] = *(const i32x4*)&Bs[buf][nr][fsw];
    }
    __builtin_amdgcn_s_setprio(1);
#pragma unroll
    for (int mi = 0; mi < 4; ++mi) {
      int ar = wr + mi * 16 + (l & 15);
      i32x4 a = *(const i32x4*)&As[buf][ar][fsw];
#pragma unroll
      for (int ni = 0; ni < 2; ++ni)
        acc[mi][ni] = __builtin_amdgcn_mfma_i32_16x16x64_i8(a, b[ni], acc[mi][ni], 0, 0, 0);
    }
    __builtin_amdgcn_s_setprio(0);
  };

  const int NT = KDIM / 64;  // 64
  stage(0, 0); stage(1, 64); stage(2, 128); stage(3, 192);
  VMCNT(6);
  SB0;
  __builtin_amdgcn_s_barrier();

  for (int t = 0; t < NT; ++t) {
    compute(t & 3);
    if (t == NT - 1) break;
    LGKMCNT0; SB0;
    __builtin_amdgcn_s_barrier();
    if (t + 4 < NT) {
      stage(t & 3, (t + 4) * 64);
      VMCNT(6);
    } else if (t + 3 < NT) {
      VMCNT(4);
    } else if (t + 2 < NT) {
      VMCNT(2);
    } else {
      VMCNT(0);
    }
    SB0;
    __builtin_amdgcn_s_barrier();
  }

  const int mbase = mb * 128 + wr + ((l >> 4) << 2);
  const int nbase = nb * 128 + wc + (l & 15);
#pragma unroll
  for (int mi = 0; mi < 4; ++mi)
#pragma unroll
    for (int ni = 0; ni < 2; ++ni)
#pragma unroll
      for (int j = 0; j < 4; ++j) {
        int s = acc[mi][ni][j];
        int sg = (s > 0) - (s < 0);
        size_t off = (size_t)(mbase + mi * 16 + j) * NDIM + (nbase + ni * 16);
        if (F32OUT)
          ((float*)outp)[off] = (float)sg;
        else
          ((int8_t*)outp)[off] = (int8_t)sg;
      }
}

extern "C" void kernel_launch(void* const* d_in, const int* in_sizes, int n_in,
                              void* d_out, int out_size, void* d_ws, size_t ws_size,
                              hipStream_t stream) {
  (void)in_sizes; (void)n_in; (void)out_size; (void)ws_size;
  const float* x  = (const float*)d_in[0];
  const float* W0 = (const float*)d_in[1];
  const float* W1 = (const float*)d_in[2];
  const float* W2 = (const float*)d_in[3];
  float* out = (float*)d_out;

  const size_t QB = (size_t)KDIM * NDIM;   // 16.78 MB each
  const size_t HB = (size_t)MDIM * NDIM;   // 33.55 MB each
  int8_t* Qt0 = (int8_t*)d_ws;
  int8_t* Qt1 = Qt0 + QB;
  int8_t* Qt2 = Qt1 + QB;
  int8_t* h0  = Qt2 + QB;
  int8_t* h1  = h0 + HB;                   // ws total: 117.4 MB

  int8_t* dig = (int8_t*)d_out;            // 3 planes = 100.7 MB
  int2* flags = (int2*)((char*)d_out + 3 * HB);
  int* cnt = (int*)((char*)d_out + 3 * HB + (size_t)MAXFLAGS * 8);

  dim3 tgrid(NDIM / 64, KDIM / 64);
  k_tern<<<tgrid, 256, 0, stream>>>(W0, Qt0);
  k_tern<<<tgrid, 256, 0, stream>>>(W1, Qt1);
  k_tern<<<tgrid, 256, 0, stream>>>(W2, Qt2);
  k_quant<<<((size_t)MDIM * KDIM) / 1024, 256, 0, stream>>>(x, dig);
  k_zero<<<1, 64, 0, stream>>>(cnt);
  k_gemm_l1<<<(MDIM / 64) * (NDIM / 128), 512, 0, stream>>>(dig, Qt0, h0, cnt, flags);
  k_fixup<<<512, 256, 0, stream>>>(x, Qt0, cnt, flags, h0);
  k_gemm_bin<0><<<(MDIM / 128) * (NDIM / 128), 512, 0, stream>>>(h0, Qt1, h1);
  k_gemm_bin<1><<<(MDIM / 128) * (NDIM / 128), 512, 0, stream>>>(h1, Qt2, out);
}

// Round 5
// 793.963 us; speedup vs baseline: 1.1697x; 1.1697x over previous
//
#include <hip/hip_runtime.h>
#include <stdint.h>

#define MDIM 8192
#define KDIM 4096
#define NDIM 4096
#define MAXFLAGS (2 * 1024 * 1024)

typedef int i32x4 __attribute__((ext_vector_type(4)));

#define VMCNT(n) asm volatile("s_waitcnt vmcnt(" #n ")" ::: "memory")
#define LGKMCNT0 asm volatile("s_waitcnt lgkmcnt(0)" ::: "memory")
#define SB0 __builtin_amdgcn_sched_barrier(0)

__device__ __forceinline__ void gl2lds16(const void* g, void* l) {
  __builtin_amdgcn_global_load_lds(
      (const __attribute__((address_space(1))) void*)(uintptr_t)(g),
      (__attribute__((address_space(3))) void*)(uintptr_t)(l), 16, 0, 0);
}

// ---------------- ternarize + transpose: Qt[n][k] = clip(rint(W[k][n]),-1,1) ----------------
__global__ __launch_bounds__(256) void k_tern(const float* __restrict__ W,
                                              int8_t* __restrict__ Qt) {
  __shared__ int8_t t[64][65];
  const int n0 = blockIdx.x * 64;
  const int k0 = blockIdx.y * 64;
  const int tid = threadIdx.x;
  const int c = tid & 63;
  const int r0 = tid >> 6;
#pragma unroll
  for (int i = 0; i < 16; ++i) {
    int r = (i << 2) + r0;
    float w = W[(size_t)(k0 + r) * NDIM + (n0 + c)];
    float q = fminf(1.f, fmaxf(-1.f, rintf(w)));  // rint = round-half-even, matches jnp.round
    t[r][c] = (int8_t)(int)q;
  }
  __syncthreads();
#pragma unroll
  for (int i = 0; i < 16; ++i) {
    int r = (i << 2) + r0;
    Qt[(size_t)(n0 + r) * KDIM + (k0 + c)] = t[c][r];
  }
}

// ---------------- quantize x to 3 signed base-256 digit planes of round(x * 2^19) ----------------
__global__ __launch_bounds__(256) void k_quant(const float* __restrict__ x,
                                               int8_t* __restrict__ dig) {
  const size_t P = (size_t)MDIM * KDIM;
  size_t i = ((size_t)blockIdx.x * 256 + threadIdx.x) * 4;
  float4 v = *(const float4*)(x + i);
  float f[4] = {v.x, v.y, v.z, v.w};
  int8_t dd[3][4];
#pragma unroll
  for (int j = 0; j < 4; ++j) {
    long long s = __double2ll_rn((double)f[j] * 524288.0);  // exact: f32->f64, *2^19
    int8_t d0 = (int8_t)s; s = (s - d0) >> 8;
    int8_t d1 = (int8_t)s; s = (s - d1) >> 8;
    int8_t d2 = (int8_t)s;  // |x|<8 guaranteed-fit
    dd[0][j] = d0; dd[1][j] = d1; dd[2][j] = d2;
  }
#pragma unroll
  for (int p = 0; p < 3; ++p) {
    char4 c4; c4.x = dd[p][0]; c4.y = dd[p][1]; c4.z = dd[p][2]; c4.w = dd[p][3];
    *(char4*)(dig + p * P + i) = c4;
  }
}

__global__ void k_zero(int* c) {
  if (threadIdx.x == 0 && blockIdx.x == 0) *c = 0;
}

// ---------------- layer 1: 3 digit planes x Qt -> sign -> h0 (i8), flag |sum|<=2048 ----------------
// tile: stacked-A 192(3 planes x 64 rows) x 256, BK=128, 12 waves (3 planes x 4 col-quarters),
// per-wave 64x64 per plane. dbuf 112KB, R3-proven sync ledger, per-role vmcnt.
__global__ __launch_bounds__(768, 3) void k_gemm_l1(const int8_t* __restrict__ dig,
                                                    const int8_t* __restrict__ Qt,
                                                    int8_t* __restrict__ h,
                                                    int* __restrict__ cnt,
                                                    int2* __restrict__ flags) {
  __shared__ __align__(16) int8_t smem[114688];  // 2 x (A 24KB + B 32KB)
  const int tid = threadIdx.x;
  const int w = tid >> 6, l = tid & 63;
  const size_t P = (size_t)MDIM * KDIM;

  const int nwg = gridDim.x;                                   // 2048, %8==0
  const int wg = (blockIdx.x & 7) * (nwg >> 3) + (blockIdx.x >> 3);
  const int NB = NDIM / 256;                                   // 16
  const int mb = wg / NB, nb = wg % NB;
  const int p = w >> 2, q = w & 3;
  const int wc = q * 64;

  // staging: 56 wave-loads (A flat rows 0..191 = 24, B rows 0..255 = 32); wave w takes i=w+12s
  const int cs = ((l & 7) ^ ((l >> 3) & 7)) << 4;  // pre-swizzled 16B chunk (key = row&7 = (l>>3))
  const int8_t* gsrc[5];
  int doff[5];
#pragma unroll
  for (int s = 0; s < 5; ++s) {
    int i = w + 12 * s;
    if (i >= 56) { gsrc[s] = nullptr; doff[s] = 0; continue; }
    int r = i * 8 + (l >> 3);
    const int8_t* base;
    if (i < 24) base = dig + (size_t)(r >> 6) * P + (size_t)(mb * 64 + (r & 63)) * KDIM;
    else        base = Qt + (size_t)(nb * 256 + (r - 192)) * KDIM;
    gsrc[s] = base + cs;
    doff[s] = i * 1024 + l * 16;  // linear dest: A at [0,24K), B at [24K,56K)
  }

  i32x4 acc[4][4];
#pragma unroll
  for (int mi = 0; mi < 4; ++mi)
#pragma unroll
    for (int ni = 0; ni < 4; ++ni) acc[mi][ni] = (i32x4){0, 0, 0, 0};

  auto stage = [&](int buf, int kk) {
#pragma unroll
    for (int s = 0; s < 5; ++s) {
      int i = w + 12 * s;
      if (i < 56) gl2lds16(gsrc[s] + kk, smem + buf * 57344 + doff[s]);
    }
  };

  auto compute = [&](int buf) {
    const int8_t* sb = smem + buf * 57344;
#pragma unroll
    for (int ki = 0; ki < 2; ++ki) {
      const int kg = ki * 4 + (l >> 4);
      i32x4 b[4], a[4];
#pragma unroll
      for (int ni = 0; ni < 4; ++ni) {
        int nr = wc + ni * 16 + (l & 15);
        b[ni] = *(const i32x4*)(sb + 24576 + nr * 128 + ((kg ^ (nr & 7)) << 4));
      }
#pragma unroll
      for (int mi = 0; mi < 4; ++mi) {
        int ar = mi * 16 + (l & 15);
        a[mi] = *(const i32x4*)(sb + p * 8192 + ar * 128 + ((kg ^ (ar & 7)) << 4));
      }
      __builtin_amdgcn_s_setprio(1);
#pragma unroll
      for (int mi = 0; mi < 4; ++mi)
#pragma unroll
        for (int ni = 0; ni < 4; ++ni)
          acc[mi][ni] =
              __builtin_amdgcn_mfma_i32_16x16x64_i8(a[mi], b[ni], acc[mi][ni], 0, 0, 0);
      __builtin_amdgcn_s_setprio(0);
    }
  };

  const int NT = KDIM / 128;  // 32
  stage(0, 0); stage(1, 128);
  if (w < 8) VMCNT(5); else VMCNT(4);  // tile0 landed, tile1 in flight
  SB0;
  __builtin_amdgcn_s_barrier();

  for (int t = 0; t < NT; ++t) {
    compute(t & 1);
    if (t == NT - 1) break;
    LGKMCNT0; SB0;
    __builtin_amdgcn_s_barrier();          // all waves done reading buf t&1
    if (t + 2 < NT) {
      stage(t & 1, (t + 2) * 128);
      if (w < 8) VMCNT(5); else VMCNT(4);  // tile t+1 landed
    } else {
      VMCNT(0);
    }
    SB0;
    __builtin_amdgcn_s_barrier();          // tile t+1 visible
  }

  // ---- epilogue: cross-plane combine via LDS (regions: q*16KB, 64KB total) ----
  LGKMCNT0; SB0;
  __builtin_amdgcn_s_barrier();            // K-loop LDS reads drained block-wide
  if (p == 1) {
#pragma unroll
    for (int mi = 0; mi < 4; ++mi)
#pragma unroll
      for (int ni = 0; ni < 4; ++ni)
        *(i32x4*)(smem + q * 16384 + ((mi * 4 + ni) * 64 + l) * 16) = acc[mi][ni];
  }
  LGKMCNT0; SB0;
  __builtin_amdgcn_s_barrier();
  if (p == 0) {
#pragma unroll
    for (int mi = 0; mi < 4; ++mi)
#pragma unroll
      for (int ni = 0; ni < 4; ++ni) {
        i32x4 s1 = *(const i32x4*)(smem + q * 16384 + ((mi * 4 + ni) * 64 + l) * 16);
        acc[mi][ni] += (s1 << 8);  // s01 = s0 + 256*s1, |.| < 2^28, exact i32
      }
  }
  LGKMCNT0; SB0;
  __builtin_amdgcn_s_barrier();
  if (p == 2) {
#pragma unroll
    for (int mi = 0; mi < 4; ++mi)
#pragma unroll
      for (int ni = 0; ni < 4; ++ni)
        *(i32x4*)(smem + q * 16384 + ((mi * 4 + ni) * 64 + l) * 16) = acc[mi][ni];
  }
  LGKMCNT0; SB0;
  __builtin_amdgcn_s_barrier();
  if (p == 0) {
    const int mbase = mb * 64 + ((l >> 4) << 2);
    const int nbase = nb * 256 + q * 64 + (l & 15);
#pragma unroll
    for (int mi = 0; mi < 4; ++mi)
#pragma unroll
      for (int ni = 0; ni < 4; ++ni) {
        i32x4 s2 = *(const i32x4*)(smem + q * 16384 + ((mi * 4 + ni) * 64 + l) * 16);
#pragma unroll
        for (int j = 0; j < 4; ++j) {
          // d = s0 + 256 s1 + 65536 s2, exact in f64 (|.| < 2^45)
          double dd = (double)s2[j] * 65536.0 + (double)acc[mi][ni][j];
          int sg = (dd > 0.0) - (dd < 0.0);
          int row = mbase + mi * 16 + j;
          int col = nbase + ni * 16;
          h[(size_t)row * NDIM + col] = (int8_t)sg;
          if (fabs(dd) <= 2048.0) {  // certified: |d - 2^19*exact| <= 0.5*4096
            int idx = atomicAdd(cnt, 1);
            if (idx < MAXFLAGS) flags[idx] = make_int2(row, col);
          }
        }
      }
  }
}

// ---------------- exact f64 fixup of flagged (row,col) outputs ----------------
__global__ __launch_bounds__(256) void k_fixup(const float* __restrict__ x,
                                               const int8_t* __restrict__ Qt,
                                               const int* __restrict__ cnt,
                                               const int2* __restrict__ flags,
                                               int8_t* __restrict__ h) {
  __shared__ double red[256];
  int n = *cnt;
  if (n > MAXFLAGS) n = MAXFLAGS;
  for (int i = blockIdx.x; i < n; i += gridDim.x) {
    int2 rc = flags[i];
    const float* xr = x + (size_t)rc.x * KDIM;
    const int8_t* qr = Qt + (size_t)rc.y * KDIM;
    double s = 0.0;
    for (int k = threadIdx.x; k < KDIM; k += 256)
      s += (double)xr[k] * (double)qr[k];
    red[threadIdx.x] = s;
    __syncthreads();
#pragma unroll
    for (int st = 128; st > 0; st >>= 1) {
      if (threadIdx.x < st) red[threadIdx.x] += red[threadIdx.x + st];
      __syncthreads();
    }
    if (threadIdx.x == 0) {
      double d = red[0];
      h[(size_t)rc.x * NDIM + rc.y] = (int8_t)((d > 0.0) - (d < 0.0));
    }
    __syncthreads();
  }
}

// ---------------- layers 2/3: h (i8 +-1/0) x Qt -> sign -> i8 or f32 ----------------
// tile 256x256, BK=128, 8 waves (2x4), per-wave 128x64. dbuf 128KB, 1 block/CU.
template <int F32OUT>
__global__ __launch_bounds__(512, 2) void k_gemm_bin(const int8_t* __restrict__ A,
                                                     const int8_t* __restrict__ Qt,
                                                     void* __restrict__ outp) {
  __shared__ __align__(16) int8_t smem[131072];  // 2 x (A 32KB + B 32KB)
  const int tid = threadIdx.x;
  const int w = tid >> 6, l = tid & 63;

  const int nwg = gridDim.x;                                   // 512, %8==0
  const int wg = (blockIdx.x & 7) * (nwg >> 3) + (blockIdx.x >> 3);
  const int NB = NDIM / 256;                                   // 16
  const int mb = wg / NB, nb = wg % NB;

  const int cs = ((l & 7) ^ ((l >> 3) & 7)) << 4;
  const int r0 = w * 32 + (l >> 3);
  const int8_t* gA[4];
  const int8_t* gB[4];
#pragma unroll
  for (int s = 0; s < 4; ++s) {
    gA[s] = A + (size_t)(mb * 256 + r0 + s * 8) * KDIM + cs;
    gB[s] = Qt + (size_t)(nb * 256 + r0 + s * 8) * KDIM + cs;
  }
  const int dA = w * 4096 + l * 16;

  i32x4 acc[8][4];
#pragma unroll
  for (int mi = 0; mi < 8; ++mi)
#pragma unroll
    for (int ni = 0; ni < 4; ++ni) acc[mi][ni] = (i32x4){0, 0, 0, 0};

  const int wr = (w >> 2) * 128, wc = (w & 3) * 64;

  auto stage = [&](int buf, int kk) {
    int8_t* sb = smem + buf * 65536;
#pragma unroll
    for (int s = 0; s < 4; ++s) gl2lds16(gA[s] + kk, sb + dA + s * 1024);
#pragma unroll
    for (int s = 0; s < 4; ++s) gl2lds16(gB[s] + kk, sb + 32768 + dA + s * 1024);
  };

  auto compute = [&](int buf) {
    const int8_t* sb = smem + buf * 65536;
#pragma unroll
    for (int ki = 0; ki < 2; ++ki) {
      const int kg = ki * 4 + (l >> 4);
      i32x4 b[4], a[8];
#pragma unroll
      for (int ni = 0; ni < 4; ++ni) {
        int nr = wc + ni * 16 + (l & 15);
        b[ni] = *(const i32x4*)(sb + 32768 + nr * 128 + ((kg ^ (nr & 7)) << 4));
      }
#pragma unroll
      for (int mi = 0; mi < 8; ++mi) {
        int ar = wr + mi * 16 + (l & 15);
        a[mi] = *(const i32x4*)(sb + ar * 128 + ((kg ^ (ar & 7)) << 4));
      }
      __builtin_amdgcn_s_setprio(1);
#pragma unroll
      for (int mi = 0; mi < 8; ++mi)
#pragma unroll
        for (int ni = 0; ni < 4; ++ni)
          acc[mi][ni] =
              __builtin_amdgcn_mfma_i32_16x16x64_i8(a[mi], b[ni], acc[mi][ni], 0, 0, 0);
      __builtin_amdgcn_s_setprio(0);
    }
  };

  const int NT = KDIM / 128;  // 32
  stage(0, 0); stage(1, 128);
  VMCNT(8);
  SB0;
  __builtin_amdgcn_s_barrier();

  for (int t = 0; t < NT; ++t) {
    compute(t & 1);
    if (t == NT - 1) break;
    LGKMCNT0; SB0;
    __builtin_amdgcn_s_barrier();
    if (t + 2 < NT) {
      stage(t & 1, (t + 2) * 128);
      VMCNT(8);
    } else {
      VMCNT(0);
    }
    SB0;
    __builtin_amdgcn_s_barrier();
  }

  const int mbase = mb * 256 + wr + ((l >> 4) << 2);
  const int nbase = nb * 256 + wc + (l & 15);
#pragma unroll
  for (int mi = 0; mi < 8; ++mi)
#pragma unroll
    for (int ni = 0; ni < 4; ++ni)
#pragma unroll
      for (int j = 0; j < 4; ++j) {
        int s = acc[mi][ni][j];
        int sg = (s > 0) - (s < 0);
        size_t off = (size_t)(mbase + mi * 16 + j) * NDIM + (nbase + ni * 16);
        if (F32OUT)
          ((float*)outp)[off] = (float)sg;
        else
          ((int8_t*)outp)[off] = (int8_t)sg;
      }
}

extern "C" void kernel_launch(void* const* d_in, const int* in_sizes, int n_in,
                              void* d_out, int out_size, void* d_ws, size_t ws_size,
                              hipStream_t stream) {
  (void)in_sizes; (void)n_in; (void)out_size; (void)ws_size;
  const float* x  = (const float*)d_in[0];
  const float* W0 = (const float*)d_in[1];
  const float* W1 = (const float*)d_in[2];
  const float* W2 = (const float*)d_in[3];
  float* out = (float*)d_out;

  const size_t QB = (size_t)KDIM * NDIM;   // 16.78 MB each
  const size_t HB = (size_t)MDIM * NDIM;   // 33.55 MB each
  int8_t* Qt0 = (int8_t*)d_ws;
  int8_t* Qt1 = Qt0 + QB;
  int8_t* Qt2 = Qt1 + QB;
  int8_t* h0  = Qt2 + QB;
  int8_t* h1  = h0 + HB;                   // ws total: 117.4 MB

  int8_t* dig = (int8_t*)d_out;            // 3 planes = 100.7 MB
  int2* flags = (int2*)((char*)d_out + 3 * HB);
  int* cnt = (int*)((char*)d_out + 3 * HB + (size_t)MAXFLAGS * 8);

  dim3 tgrid(NDIM / 64, KDIM / 64);
  k_tern<<<tgrid, 256, 0, stream>>>(W0, Qt0);
  k_tern<<<tgrid, 256, 0, stream>>>(W1, Qt1);
  k_tern<<<tgrid, 256, 0, stream>>>(W2, Qt2);
  k_quant<<<((size_t)MDIM * KDIM) / 1024, 256, 0, stream>>>(x, dig);
  k_zero<<<1, 64, 0, stream>>>(cnt);
  k_gemm_l1<<<(MDIM / 64) * (NDIM / 256), 768, 0, stream>>>(dig, Qt0, h0, cnt, flags);
  k_fixup<<<512, 256, 0, stream>>>(x, Qt0, cnt, flags, h0);
  k_gemm_bin<0><<<(MDIM / 256) * (NDIM / 256), 512, 0, stream>>>(h0, Qt1, h1);
  k_gemm_bin<1><<<(MDIM / 256) * (NDIM / 256), 512, 0, stream>>>(h1, Qt2, out);
}

// Round 6
// 753.474 us; speedup vs baseline: 1.2326x; 1.0537x over previous
//
#include <hip/hip_runtime.h>
#include <stdint.h>

#define MDIM 8192
#define KDIM 4096
#define NDIM 4096
#define MAXFLAGS (2 * 1024 * 1024)

typedef int i32x4 __attribute__((ext_vector_type(4)));

#define VMCNT(n) asm volatile("s_waitcnt vmcnt(" #n ")" ::: "memory")
#define LGKMCNT0 asm volatile("s_waitcnt lgkmcnt(0)" ::: "memory")
#define SB0 __builtin_amdgcn_sched_barrier(0)

__device__ __forceinline__ void gl2lds16(const void* g, void* l) {
  __builtin_amdgcn_global_load_lds(
      (const __attribute__((address_space(1))) void*)(uintptr_t)(g),
      (__attribute__((address_space(3))) void*)(uintptr_t)(l), 16, 0, 0);
}

// ---------------- ternarize + transpose: Qt[n][k] = clip(rint(W[k][n]),-1,1) ----------------
__global__ __launch_bounds__(256) void k_tern(const float* __restrict__ W,
                                              int8_t* __restrict__ Qt) {
  __shared__ int8_t t[64][65];
  const int n0 = blockIdx.x * 64;
  const int k0 = blockIdx.y * 64;
  const int tid = threadIdx.x;
  const int c = tid & 63;
  const int r0 = tid >> 6;
#pragma unroll
  for (int i = 0; i < 16; ++i) {
    int r = (i << 2) + r0;
    float w = W[(size_t)(k0 + r) * NDIM + (n0 + c)];
    float q = fminf(1.f, fmaxf(-1.f, rintf(w)));  // rint = round-half-even, matches jnp.round
    t[r][c] = (int8_t)(int)q;
  }
  __syncthreads();
#pragma unroll
  for (int i = 0; i < 16; ++i) {
    int r = (i << 2) + r0;
    Qt[(size_t)(n0 + r) * KDIM + (k0 + c)] = t[c][r];
  }
}

// ---------------- quantize x to 3 signed base-256 digit planes of round(x * 2^19) ----------------
__global__ __launch_bounds__(256) void k_quant(const float* __restrict__ x,
                                               int8_t* __restrict__ dig) {
  const size_t P = (size_t)MDIM * KDIM;
  size_t i = ((size_t)blockIdx.x * 256 + threadIdx.x) * 4;
  float4 v = *(const float4*)(x + i);
  float f[4] = {v.x, v.y, v.z, v.w};
  int8_t dd[3][4];
#pragma unroll
  for (int j = 0; j < 4; ++j) {
    long long s = __double2ll_rn((double)f[j] * 524288.0);  // exact: f32->f64, *2^19
    int8_t d0 = (int8_t)s; s = (s - d0) >> 8;
    int8_t d1 = (int8_t)s; s = (s - d1) >> 8;
    int8_t d2 = (int8_t)s;  // |x|<8 guaranteed-fit
    dd[0][j] = d0; dd[1][j] = d1; dd[2][j] = d2;
  }
#pragma unroll
  for (int p = 0; p < 3; ++p) {
    char4 c4; c4.x = dd[p][0]; c4.y = dd[p][1]; c4.z = dd[p][2]; c4.w = dd[p][3];
    *(char4*)(dig + p * P + i) = c4;
  }
}

__global__ void k_zero(int* c) {
  if (threadIdx.x == 0 && blockIdx.x == 0) *c = 0;
}

// ---------------- layer 1 (R3-proven): 3 planes x Qt -> sign -> h0, flag |sum|<=2048 ----------------
// dbuf BK=128, tile 64x128, 8 waves, per-wave 32x32, 80KB LDS -> 2 blocks/CU.
__global__ __launch_bounds__(512) void k_gemm_l1(const int8_t* __restrict__ dig,
                                                 const int8_t* __restrict__ Qt,
                                                 int8_t* __restrict__ h,
                                                 int* __restrict__ cnt,
                                                 int2* __restrict__ flags) {
  __shared__ __align__(16) int8_t As[2][3][64][128];  // 48KB
  __shared__ __align__(16) int8_t Bs[2][128][128];    // 32KB
  const int tid = threadIdx.x;
  const int w = tid >> 6, l = tid & 63;
  const size_t P = (size_t)MDIM * KDIM;

  const int nwg = gridDim.x;                                   // 4096, %8==0
  const int wg = (blockIdx.x & 7) * (nwg >> 3) + (blockIdx.x >> 3);
  const int NB = NDIM / 128;                                   // 32
  const int mb = wg / NB, nb = wg % NB;

  const int srow = tid >> 3;          // 0..63
  const int sswz = (tid & 7) ^ (srow & 7);
  const int8_t* a_src = dig + (size_t)(mb * 64 + srow) * KDIM + sswz * 16;
  const int8_t* b_src0 = Qt + (size_t)(nb * 128 + srow) * KDIM + sswz * 16;
  const int8_t* b_src1 = b_src0 + (size_t)64 * KDIM;

  i32x4 acc[3][2][2];
#pragma unroll
  for (int p = 0; p < 3; ++p)
#pragma unroll
    for (int mi = 0; mi < 2; ++mi)
#pragma unroll
      for (int ni = 0; ni < 2; ++ni) acc[p][mi][ni] = (i32x4){0, 0, 0, 0};

  const int wr = (w >> 2) * 32;
  const int wc = (w & 3) * 32;

  auto stage = [&](int buf, int kk) {
    int8_t* ad = &As[buf][0][0][0] + w * 1024;
    int8_t* bd = &Bs[buf][0][0] + w * 1024;
#pragma unroll
    for (int p = 0; p < 3; ++p) gl2lds16(a_src + p * P + kk, ad + p * 8192);
    gl2lds16(b_src0 + kk, bd);
    gl2lds16(b_src1 + kk, bd + 8192);
  };

  auto compute = [&](int buf) {
#pragma unroll
    for (int ki = 0; ki < 2; ++ki) {
      const int kg = ki * 4 + (l >> 4);
      i32x4 b[2];
#pragma unroll
      for (int ni = 0; ni < 2; ++ni) {
        int nr = wc + ni * 16 + (l & 15);
        b[ni] = *(const i32x4*)&Bs[buf][nr][(kg ^ (nr & 7)) * 16];
      }
      __builtin_amdgcn_s_setprio(1);
#pragma unroll
      for (int p = 0; p < 3; ++p)
#pragma unroll
        for (int mi = 0; mi < 2; ++mi) {
          int ar = wr + mi * 16 + (l & 15);
          i32x4 a = *(const i32x4*)&As[buf][p][ar][(kg ^ (ar & 7)) * 16];
#pragma unroll
          for (int ni = 0; ni < 2; ++ni)
            acc[p][mi][ni] =
                __builtin_amdgcn_mfma_i32_16x16x64_i8(a, b[ni], acc[p][mi][ni], 0, 0, 0);
        }
      __builtin_amdgcn_s_setprio(0);
    }
  };

  // prologue: tiles 0,1 in flight; wait tile0 (allow tile1's 5 loads outstanding)
  stage(0, 0);
  stage(1, 128);
  VMCNT(5);
  SB0;
  __builtin_amdgcn_s_barrier();

  const int NT = KDIM / 128;  // 32
  for (int t = 0; t < NT; ++t) {
    compute(t & 1);
    if (t == NT - 1) break;
    LGKMCNT0; SB0;
    __builtin_amdgcn_s_barrier();               // all waves done reading buf[t&1]
    if (t + 2 < NT) {
      stage(t & 1, (t + 2) * 128);              // overwrite buf[t&1] with tile t+2
      VMCNT(5);                                 // tile t+1 landed; t+2 in flight
    } else {
      VMCNT(0);
    }
    SB0;
    __builtin_amdgcn_s_barrier();               // tile t+1 visible to all
  }

  const int mbase = mb * 64 + wr + ((l >> 4) << 2);
  const int nbase = nb * 128 + wc + (l & 15);
#pragma unroll
  for (int mi = 0; mi < 2; ++mi)
#pragma unroll
    for (int ni = 0; ni < 2; ++ni)
#pragma unroll
      for (int j = 0; j < 4; ++j) {
        int s0 = acc[0][mi][ni][j], s1 = acc[1][mi][ni][j];
        int s2 = acc[2][mi][ni][j];
        double d = ((double)s2 * 256.0 + (double)s1) * 256.0 + (double)s0;
        int sg = (d > 0.0) - (d < 0.0);
        int row = mbase + mi * 16 + j;
        int col = nbase + ni * 16;
        h[(size_t)row * NDIM + col] = (int8_t)sg;
        if (fabs(d) <= 2048.0) {  // certified: |d - 2^19*exact| <= 0.5*4096
          int idx = atomicAdd(cnt, 1);
          if (idx < MAXFLAGS) flags[idx] = make_int2(row, col);
        }
      }
}

// ---------------- exact f64 fixup of flagged (row,col) outputs ----------------
__global__ __launch_bounds__(256) void k_fixup(const float* __restrict__ x,
                                               const int8_t* __restrict__ Qt,
                                               const int* __restrict__ cnt,
                                               const int2* __restrict__ flags,
                                               int8_t* __restrict__ h) {
  __shared__ double red[256];
  int n = *cnt;
  if (n > MAXFLAGS) n = MAXFLAGS;
  for (int i = blockIdx.x; i < n; i += gridDim.x) {
    int2 rc = flags[i];
    const float* xr = x + (size_t)rc.x * KDIM;
    const int8_t* qr = Qt + (size_t)rc.y * KDIM;
    double s = 0.0;
    for (int k = threadIdx.x; k < KDIM; k += 256)
      s += (double)xr[k] * (double)qr[k];
    red[threadIdx.x] = s;
    __syncthreads();
#pragma unroll
    for (int st = 128; st > 0; st >>= 1) {
      if (threadIdx.x < st) red[threadIdx.x] += red[threadIdx.x + st];
      __syncthreads();
    }
    if (threadIdx.x == 0) {
      double d = red[0];
      h[(size_t)rc.x * NDIM + rc.y] = (int8_t)((d > 0.0) - (d < 0.0));
    }
    __syncthreads();
  }
}

// ---------------- layers 2/3 (R5-proven): 256x256xBK128 dbuf, 8 waves, per-wave 128x64 ----------------
template <int F32OUT>
__global__ __launch_bounds__(512, 2) void k_gemm_bin(const int8_t* __restrict__ A,
                                                     const int8_t* __restrict__ Qt,
                                                     void* __restrict__ outp) {
  __shared__ __align__(16) int8_t smem[131072];  // 2 x (A 32KB + B 32KB)
  const int tid = threadIdx.x;
  const int w = tid >> 6, l = tid & 63;

  const int nwg = gridDim.x;                                   // 512, %8==0
  const int wg = (blockIdx.x & 7) * (nwg >> 3) + (blockIdx.x >> 3);
  const int NB = NDIM / 256;                                   // 16
  const int mb = wg / NB, nb = wg % NB;

  const int cs = ((l & 7) ^ ((l >> 3) & 7)) << 4;
  const int r0 = w * 32 + (l >> 3);
  const int8_t* gA[4];
  const int8_t* gB[4];
#pragma unroll
  for (int s = 0; s < 4; ++s) {
    gA[s] = A + (size_t)(mb * 256 + r0 + s * 8) * KDIM + cs;
    gB[s] = Qt + (size_t)(nb * 256 + r0 + s * 8) * KDIM + cs;
  }
  const int dA = w * 4096 + l * 16;

  i32x4 acc[8][4];
#pragma unroll
  for (int mi = 0; mi < 8; ++mi)
#pragma unroll
    for (int ni = 0; ni < 4; ++ni) acc[mi][ni] = (i32x4){0, 0, 0, 0};

  const int wr = (w >> 2) * 128, wc = (w & 3) * 64;

  auto stage = [&](int buf, int kk) {
    int8_t* sb = smem + buf * 65536;
#pragma unroll
    for (int s = 0; s < 4; ++s) gl2lds16(gA[s] + kk, sb + dA + s * 1024);
#pragma unroll
    for (int s = 0; s < 4; ++s) gl2lds16(gB[s] + kk, sb + 32768 + dA + s * 1024);
  };

  auto compute = [&](int buf) {
    const int8_t* sb = smem + buf * 65536;
#pragma unroll
    for (int ki = 0; ki < 2; ++ki) {
      const int kg = ki * 4 + (l >> 4);
      i32x4 b[4], a[8];
#pragma unroll
      for (int ni = 0; ni < 4; ++ni) {
        int nr = wc + ni * 16 + (l & 15);
        b[ni] = *(const i32x4*)(sb + 32768 + nr * 128 + ((kg ^ (nr & 7)) << 4));
      }
#pragma unroll
      for (int mi = 0; mi < 8; ++mi) {
        int ar = wr + mi * 16 + (l & 15);
        a[mi] = *(const i32x4*)(sb + ar * 128 + ((kg ^ (ar & 7)) << 4));
      }
      __builtin_amdgcn_s_setprio(1);
#pragma unroll
      for (int mi = 0; mi < 8; ++mi)
#pragma unroll
        for (int ni = 0; ni < 4; ++ni)
          acc[mi][ni] =
              __builtin_amdgcn_mfma_i32_16x16x64_i8(a[mi], b[ni], acc[mi][ni], 0, 0, 0);
      __builtin_amdgcn_s_setprio(0);
    }
  };

  const int NT = KDIM / 128;  // 32
  stage(0, 0); stage(1, 128);
  VMCNT(8);
  SB0;
  __builtin_amdgcn_s_barrier();

  for (int t = 0; t < NT; ++t) {
    compute(t & 1);
    if (t == NT - 1) break;
    LGKMCNT0; SB0;
    __builtin_amdgcn_s_barrier();
    if (t + 2 < NT) {
      stage(t & 1, (t + 2) * 128);
      VMCNT(8);
    } else {
      VMCNT(0);
    }
    SB0;
    __builtin_amdgcn_s_barrier();
  }

  const int mbase = mb * 256 + wr + ((l >> 4) << 2);
  const int nbase = nb * 256 + wc + (l & 15);
#pragma unroll
  for (int mi = 0; mi < 8; ++mi)
#pragma unroll
    for (int ni = 0; ni < 4; ++ni)
#pragma unroll
      for (int j = 0; j < 4; ++j) {
        int s = acc[mi][ni][j];
        int sg = (s > 0) - (s < 0);
        size_t off = (size_t)(mbase + mi * 16 + j) * NDIM + (nbase + ni * 16);
        if (F32OUT)
          ((float*)outp)[off] = (float)sg;
        else
          ((int8_t*)outp)[off] = (int8_t)sg;
      }
}

extern "C" void kernel_launch(void* const* d_in, const int* in_sizes, int n_in,
                              void* d_out, int out_size, void* d_ws, size_t ws_size,
                              hipStream_t stream) {
  (void)in_sizes; (void)n_in; (void)out_size; (void)ws_size;
  const float* x  = (const float*)d_in[0];
  const float* W0 = (const float*)d_in[1];
  const float* W1 = (const float*)d_in[2];
  const float* W2 = (const float*)d_in[3];
  float* out = (float*)d_out;

  const size_t QB = (size_t)KDIM * NDIM;   // 16.78 MB each
  const size_t HB = (size_t)MDIM * NDIM;   // 33.55 MB each
  int8_t* Qt0 = (int8_t*)d_ws;
  int8_t* Qt1 = Qt0 + QB;
  int8_t* Qt2 = Qt1 + QB;
  int8_t* h0  = Qt2 + QB;
  int8_t* h1  = h0 + HB;                   // ws total: 117.4 MB

  int8_t* dig = (int8_t*)d_out;            // 3 planes = 100.7 MB
  int2* flags = (int2*)((char*)d_out + 3 * HB);
  int* cnt = (int*)((char*)d_out + 3 * HB + (size_t)MAXFLAGS * 8);

  dim3 tgrid(NDIM / 64, KDIM / 64);
  k_tern<<<tgrid, 256, 0, stream>>>(W0, Qt0);
  k_tern<<<tgrid, 256, 0, stream>>>(W1, Qt1);
  k_tern<<<tgrid, 256, 0, stream>>>(W2, Qt2);
  k_quant<<<((size_t)MDIM * KDIM) / 1024, 256, 0, stream>>>(x, dig);
  k_zero<<<1, 64, 0, stream>>>(cnt);
  k_gemm_l1<<<(MDIM / 64) * (NDIM / 128), 512, 0, stream>>>(dig, Qt0, h0, cnt, flags);
  k_fixup<<<512, 256, 0, stream>>>(x, Qt0, cnt, flags, h0);
  k_gemm_bin<0><<<(MDIM / 256) * (NDIM / 256), 512, 0, stream>>>(h0, Qt1, h1);
  k_gemm_bin<1><<<(MDIM / 256) * (NDIM / 256), 512, 0, stream>>>(h1, Qt2, out);
}